// Round 13
// baseline (794.462 us; speedup 1.0000x reference)
//
#include <hip/hip_runtime.h>

typedef unsigned short u16;
typedef unsigned int u32;
typedef float f32x4 __attribute__((ext_vector_type(4)));
typedef short bf16x8 __attribute__((ext_vector_type(8)));

#define DIM 2048
#define SEQ 2048
#define NHEAD 16
#define HDIM 128
#define BATCH 2
#define HIDDEN 5632
#define ROWS 4096  // BATCH*SEQ

__device__ __forceinline__ float b2f(u16 h) { return __uint_as_float(((u32)h) << 16); }
__device__ __forceinline__ u16 f2b(float f) {
  u32 u = __float_as_uint(f);
  return (u16)((u + 0x7fffu + ((u >> 16) & 1u)) >> 16);
}

// ---------------- fp32 -> bf16 elementwise ----------------
__global__ __launch_bounds__(256) void cvt_f2b(const float* __restrict__ in, u16* __restrict__ out, int n) {
  int i = (blockIdx.x * 256 + threadIdx.x) * 4;
  if (i < n) {
    float4 v = *(const float4*)(in + i);
    u32 p0 = (u32)f2b(v.x) | ((u32)f2b(v.y) << 16);
    u32 p1 = (u32)f2b(v.z) | ((u32)f2b(v.w) << 16);
    *(uint2*)(out + i) = make_uint2(p0, p1);
  }
}

// ---------------- 4x fused: fp32 [2048,2048] -> bf16 transposed, z picks the weight ----------------
__global__ __launch_bounds__(256) void cvtT4(const float* __restrict__ w0, const float* __restrict__ w1,
                                             const float* __restrict__ w2, const float* __restrict__ w3,
                                             u16* __restrict__ o0, u16* __restrict__ o1,
                                             u16* __restrict__ o2, u16* __restrict__ o3) {
  const float* in = (blockIdx.z == 0) ? w0 : (blockIdx.z == 1) ? w1 : (blockIdx.z == 2) ? w2 : w3;
  u16* out = (blockIdx.z == 0) ? o0 : (blockIdx.z == 1) ? o1 : (blockIdx.z == 2) ? o2 : o3;
  __shared__ float t[32][33];
  int tx = threadIdx.x & 31, ty = threadIdx.x >> 5;
  int r0 = blockIdx.y * 32, c0 = blockIdx.x * 32;
#pragma unroll
  for (int rr = 0; rr < 4; ++rr)
    t[ty + rr * 8][tx] = in[(size_t)(r0 + ty + rr * 8) * DIM + c0 + tx];
  __syncthreads();
#pragma unroll
  for (int rr = 0; rr < 4; ++rr)
    out[(size_t)(c0 + ty + rr * 8) * DIM + r0 + tx] = f2b(t[tx][ty + rr * 8]);
}

// ================= gemm8p v2 (round-8 config): BM=128 x BN=256, BK=64 =================
// EPI: 0 bf16; 1 fp32 C=acc+fp32 R; 2 bf16 C=silu(R)*acc; 3 fp32 C=acc+bf16 R;
//      4 QKV split; 5 QKV split + fused RoPE (q scaled, q/k rotated, v passthrough)
template <int EPI>
__global__ __launch_bounds__(512, 2) void gemm8p(const u16* __restrict__ A, const u16* __restrict__ Bt,
                                                 const void* R_, void* C_, int M, int N, int K,
                                                 const float* __restrict__ FC, const float* __restrict__ FS) {
  __shared__ u16 LA[2][8192];
  __shared__ u16 LB[2][2][8192];
  const int tid = threadIdx.x;
  const int lane = tid & 63, wid = tid >> 6;
  const int wr = wid >> 2, wc = wid & 3;
  const int rl = lane & 15, g = lane >> 4;
  const int s2 = ((rl >> 3) & 1) << 1;
  const int gx = gridDim.x, gy = gridDim.y;
  const int id = blockIdx.y * gx + blockIdx.x;
  const int cpx = (gx * gy) >> 3;
  const int sw = (id & 7) * cpx + (id >> 3);
  const int m0 = (sw % gy) * 128, n0 = (sw / gy) * 256;
  const int nk = K >> 6;

  const int srow = tid >> 2;
  const int sslot = (tid & 3) ^ (((tid >> 5) & 1) << 1);

  auto SHA = [&](int ks) {
    const u16* gp = A + (size_t)(m0 + srow) * K + ks * 64 + sslot * 8;
#pragma unroll
    for (int kk = 0; kk < 2; ++kk)
      __builtin_amdgcn_global_load_lds(
          (const __attribute__((address_space(1))) void*)(gp + kk * 32),
          (__attribute__((address_space(3))) void*)&LA[ks & 1][kk * 4096 + wid * 512], 16, 0, 0);
  };
  auto SHB = [&](int ks, int hf) {
    const u16* gp = Bt + (size_t)(n0 + hf * 128 + srow) * K + ks * 64 + sslot * 8;
#pragma unroll
    for (int kk = 0; kk < 2; ++kk)
      __builtin_amdgcn_global_load_lds(
          (const __attribute__((address_space(1))) void*)(gp + kk * 32),
          (__attribute__((address_space(3))) void*)&LB[ks & 1][hf][kk * 4096 + wid * 512], 16, 0, 0);
  };

  f32x4 acc[4][4];
#pragma unroll
  for (int a = 0; a < 4; ++a)
#pragma unroll
    for (int b = 0; b < 4; ++b) acc[a][b] = (f32x4){0.f, 0.f, 0.f, 0.f};
  bf16x8 bf[4][2];

#define PH8(kst, q, STAGE, VMN)                                                                 \
  do {                                                                                          \
    const int c_ = (kst) & 1;                                                                   \
    if ((q) == 0) {                                                                             \
      _Pragma("unroll") for (int ni = 0; ni < 4; ++ni)                                          \
          _Pragma("unroll") for (int kk = 0; kk < 2; ++kk)                                      \
              bf[ni][kk] = *(const bf16x8*)&LB[c_][wc >> 1]                                     \
                  [kk * 4096 + ((wc & 1) * 64 + ni * 16 + rl) * 32 + (g ^ s2) * 8];             \
    }                                                                                           \
    bf16x8 af[2];                                                                               \
    _Pragma("unroll") for (int kk = 0; kk < 2; ++kk)                                            \
        af[kk] = *(const bf16x8*)&LA[c_]                                                        \
            [kk * 4096 + (wr * 64 + (q) * 16 + rl) * 32 + (g ^ s2) * 8];                        \
    STAGE;                                                                                      \
    __builtin_amdgcn_s_barrier();                                                               \
    asm volatile("s_waitcnt lgkmcnt(0)" ::: "memory");                                          \
    __builtin_amdgcn_sched_barrier(0);                                                          \
    __builtin_amdgcn_s_setprio(1);                                                              \
    _Pragma("unroll") for (int kk = 0; kk < 2; ++kk)                                            \
        _Pragma("unroll") for (int ni = 0; ni < 4; ++ni)                                        \
            acc[(q)][ni] = __builtin_amdgcn_mfma_f32_16x16x32_bf16(                             \
                af[kk], bf[ni][kk], acc[(q)][ni], 0, 0, 0);                                     \
    __builtin_amdgcn_s_setprio(0);                                                              \
    if ((VMN) == 4) asm volatile("s_waitcnt vmcnt(4)" ::: "memory");                            \
    else if ((VMN) == 6) asm volatile("s_waitcnt vmcnt(6)" ::: "memory");                       \
    else if ((VMN) == 0) asm volatile("s_waitcnt vmcnt(0)" ::: "memory");                       \
    __builtin_amdgcn_s_barrier();                                                               \
  } while (0)

  SHB(0, 0); SHB(0, 1); SHA(0); SHB(1, 0); SHB(1, 1); SHA(1);
  asm volatile("s_waitcnt vmcnt(6)" ::: "memory");
  __builtin_amdgcn_s_barrier();

  const int nk2 = nk >> 1;
  for (int i = 0; i < nk2; ++i) {
    const int k0 = 2 * i, k1 = 2 * i + 1;
    const bool st = (k0 + 2) < nk;
    PH8(k0, 0, , -1);
    PH8(k0, 1, if (st) SHB(k0 + 2, 0), -1);
    PH8(k0, 2, if (st) SHB(k0 + 2, 1), -1);
    PH8(k0, 3, , st ? 4 : 0);
    PH8(k1, 0, if (st) SHA(k0 + 2), -1);
    PH8(k1, 1, if (st) SHB(k0 + 3, 0), -1);
    PH8(k1, 2, if (st) SHB(k0 + 3, 1), -1);
    PH8(k1, 3, if (st) SHA(k0 + 3), st ? 6 : 0);
  }
#undef PH8

  const int sec = n0 >> 11;  // EPI 4/5: 0=q, 1=k, 2=v (block-uniform; n0 % 256 == 0)
#pragma unroll
  for (int mi = 0; mi < 4; ++mi)
#pragma unroll
    for (int ni = 0; ni < 4; ++ni)
#pragma unroll
      for (int j = 0; j < 4; ++j) {
        size_t row = m0 + wr * 64 + mi * 16 + g * 4 + j;
        size_t col = n0 + wc * 64 + ni * 16 + rl;
        size_t idx = row * N + col;
        float v = acc[mi][ni][j];
        if (EPI == 0) {
          ((u16*)C_)[idx] = f2b(v);
        } else if (EPI == 1) {
          ((float*)C_)[idx] = v + ((const float*)R_)[idx];
        } else if (EPI == 2) {
          float av = b2f(((const u16*)R_)[idx]);
          ((u16*)C_)[idx] = f2b(v * av / (1.f + __expf(-av)));
        } else if (EPI == 3) {
          ((float*)C_)[idx] = v + b2f(((const u16*)R_)[idx]);
        } else if (EPI == 4) {
          size_t di = (col >> 11) * (size_t)(ROWS * (size_t)DIM) + row * DIM + (col & (DIM - 1));
          ((u16*)C_)[di] = f2b(v);
        } else {  // EPI == 5: QKV split + fused RoPE (verified round 12, absmax 0.03125)
          float o = v;
          float p = __shfl_xor(v, 1);  // partner element (col^1) lives in lane rl^1, same regs
          if (sec < 2) {
            int s = (int)(row & (SEQ - 1));
            int ii = ((int)(col & 127)) >> 1;
            float c = FC[s * 64 + ii], sn = FS[s * 64 + ii];
            o = (rl & 1) ? (p * sn + v * c) : (v * c - p * sn);
            if (sec == 0) o *= 0.08838834764831843f;  // 1/sqrt(HDIM)
          }
          size_t di = (size_t)sec * (ROWS * (size_t)DIM) + row * DIM + (col & (DIM - 1));
          ((u16*)C_)[di] = f2b(o);
        }
      }
}

// ================= gemm_mlp: fused MLP up+gate, dual-B, silu(a)*b epilogue =================
__global__ __launch_bounds__(512, 2) void gemm_mlp(const u16* __restrict__ A, const u16* __restrict__ B1t,
                                                   const u16* __restrict__ B2t, u16* __restrict__ C,
                                                   int M, int N, int K) {
  __shared__ u16 lA[2][4096];
  __shared__ u16 lB1[2][8192];
  __shared__ u16 lB2[2][8192];
  const int tid = threadIdx.x;
  const int lane = tid & 63, wid = tid >> 6;
  const int wr = wid >> 2, wc = wid & 3;
  const int rl = lane & 15, g = lane >> 4;
  const int s2 = ((rl >> 3) & 1) << 1;
  const int gx = gridDim.x, gy = gridDim.y;
  const int id = blockIdx.y * gx + blockIdx.x;
  const int cpx = (gx * gy) >> 3;
  const int sw = (id & 7) * cpx + (id >> 3);
  const int m0 = (sw % gy) * 128, n0 = (sw / gy) * 256;
  const int nk = K >> 5;

  const int srow = tid >> 2;
  const int sslot = (tid & 3) ^ (((tid >> 5) & 1) << 1);

  auto SA = [&](int kt, int buf) {
    const u16* gp = A + (size_t)(m0 + srow) * K + kt * 32 + sslot * 8;
    __builtin_amdgcn_global_load_lds((const __attribute__((address_space(1))) void*)gp,
                                     (__attribute__((address_space(3))) void*)&lA[buf][wid * 512],
                                     16, 0, 0);
  };
  auto SB = [&](const u16* __restrict__ Bt, u16* lb, int kt) {
#pragma unroll
    for (int j = 0; j < 2; ++j) {
      const u16* gp = Bt + (size_t)(n0 + j * 128 + srow) * K + kt * 32 + sslot * 8;
      __builtin_amdgcn_global_load_lds((const __attribute__((address_space(1))) void*)gp,
                                       (__attribute__((address_space(3))) void*)(lb + j * 4096 + wid * 512),
                                       16, 0, 0);
    }
  };

  SA(0, 0); SB(B1t, lB1[0], 0); SB(B2t, lB2[0], 0);

  f32x4 ac1[4][4], ac2[4][4];
#pragma unroll
  for (int a = 0; a < 4; ++a)
#pragma unroll
    for (int b = 0; b < 4; ++b) { ac1[a][b] = (f32x4){0.f, 0.f, 0.f, 0.f}; ac2[a][b] = (f32x4){0.f, 0.f, 0.f, 0.f}; }

  __syncthreads();

  for (int kt = 0; kt < nk; ++kt) {
    const int cur = kt & 1;
    if (kt + 1 < nk) { SA(kt + 1, cur ^ 1); SB(B1t, lB1[cur ^ 1], kt + 1); SB(B2t, lB2[cur ^ 1], kt + 1); }
    bf16x8 af[4], b1[4], b2[4];
#pragma unroll
    for (int mi = 0; mi < 4; ++mi)
      af[mi] = *reinterpret_cast<const bf16x8*>(&lA[cur][(wr * 64 + mi * 16 + rl) * 32 + (g ^ s2) * 8]);
#pragma unroll
    for (int ni = 0; ni < 4; ++ni) {
      b1[ni] = *reinterpret_cast<const bf16x8*>(&lB1[cur][(wc * 64 + ni * 16 + rl) * 32 + (g ^ s2) * 8]);
      b2[ni] = *reinterpret_cast<const bf16x8*>(&lB2[cur][(wc * 64 + ni * 16 + rl) * 32 + (g ^ s2) * 8]);
    }
#pragma unroll
    for (int mi = 0; mi < 4; ++mi)
#pragma unroll
      for (int ni = 0; ni < 4; ++ni) {
        ac1[mi][ni] = __builtin_amdgcn_mfma_f32_16x16x32_bf16(af[mi], b1[ni], ac1[mi][ni], 0, 0, 0);
        ac2[mi][ni] = __builtin_amdgcn_mfma_f32_16x16x32_bf16(af[mi], b2[ni], ac2[mi][ni], 0, 0, 0);
      }
    __syncthreads();
  }

#pragma unroll
  for (int mi = 0; mi < 4; ++mi)
#pragma unroll
    for (int ni = 0; ni < 4; ++ni)
#pragma unroll
      for (int j = 0; j < 4; ++j) {
        size_t row = m0 + wr * 64 + mi * 16 + g * 4 + j;
        size_t col = n0 + wc * 64 + ni * 16 + rl;
        float a = ac1[mi][ni][j], b = ac2[mi][ni][j];
        C[row * N + col] = f2b(a / (1.f + __expf(-a)) * b);
      }
}

// ---------------- V [B,S,H,D] bf16 -> Vt [B,H,D,S] bf16 ----------------
__global__ __launch_bounds__(256) void vtrans(const u16* __restrict__ V, u16* __restrict__ Vt) {
  __shared__ u16 t[32][33];
  int tx = threadIdx.x & 31, ty = threadIdx.x >> 5;
  int s0 = blockIdx.x * 32, d0 = blockIdx.y * 32;
  int bh = blockIdx.z, b = bh >> 4, h = bh & 15;
#pragma unroll
  for (int rr = 0; rr < 4; ++rr)
    t[ty + rr * 8][tx] = V[(size_t)(b * SEQ + s0 + ty + rr * 8) * DIM + h * HDIM + d0 + tx];
  __syncthreads();
#pragma unroll
  for (int rr = 0; rr < 4; ++rr)
    Vt[(size_t)(bh * HDIM + d0 + ty + rr * 8) * SEQ + s0 + tx] = t[tx][ty + rr * 8];
}

// ---------------- flash attention (causal), r7/r11 structure (no setprio: lockstep waves) ----------------
__device__ __forceinline__ void stage_K(u16* lk, const u16* __restrict__ Kg,
                                        int b, int h, int t, int w, int lane) {
  const int r4 = lane >> 2;
  const int gsw = (lane & 3) ^ (r4 & 3);
#pragma unroll
  for (int j = 0; j < 4; ++j) {
    const u16* gp = Kg + (size_t)(b * SEQ + t * 64 + j * 16 + r4) * DIM +
                    h * HDIM + w * 32 + gsw * 8;
    __builtin_amdgcn_global_load_lds((const __attribute__((address_space(1))) void*)gp,
                                     (__attribute__((address_space(3))) void*)(lk + w * 2048 + j * 512),
                                     16, 0, 0);
  }
}

__device__ __forceinline__ void stage_V(u16* lv, const u16* __restrict__ Vg,
                                        int bh, int t, int w, int lane) {
  const int r4 = lane >> 2;
  const int gsw = (lane & 3) ^ (r4 & 3);
#pragma unroll
  for (int j = 0; j < 4; ++j) {
    int id = w * 4 + j, kc2 = id >> 3, rg = id & 7;
    const u16* gp = Vg + (size_t)(bh * HDIM + rg * 16 + r4) * SEQ +
                    t * 64 + kc2 * 32 + gsw * 8;
    __builtin_amdgcn_global_load_lds((const __attribute__((address_space(1))) void*)gp,
                                     (__attribute__((address_space(3))) void*)(lv + kc2 * 4096 + rg * 512),
                                     16, 0, 0);
  }
}

__global__ __launch_bounds__(256, 3) void attn_kernel(const u16* __restrict__ Q, const u16* __restrict__ Kp,
                                                      const u16* __restrict__ Vt, u16* __restrict__ O) {
  const int lane = threadIdx.x & 63;
  const int w = threadIdx.x >> 6;
  const int id = blockIdx.y * 32 + blockIdx.x;
  const int sw = (id & 7) * 128 + (id >> 3);
  const int qt = sw & 31;
  const int bh = sw >> 5;
  const int b = bh >> 4, h = bh & 15;
  const int rl = lane & 15, g = lane >> 4;
  const int gx8 = (g ^ (rl & 3)) * 8;

  __shared__ u16 lK[8192];
  __shared__ u16 lV[8192];
  __shared__ u16 plds[4][16][72];

  const size_t qrow = (size_t)b * SEQ + qt * 64 + w * 16;
  bf16x8 qf[4];
#pragma unroll
  for (int kc = 0; kc < 4; ++kc)
    qf[kc] = *reinterpret_cast<const bf16x8*>(Q + (qrow + rl) * DIM + h * HDIM + kc * 32 + g * 8);

  float m[4], l[4];
  f32x4 oacc[8];
#pragma unroll
  for (int j = 0; j < 4; ++j) { m[j] = -1e30f; l[j] = 0.f; }
#pragma unroll
  for (int dt = 0; dt < 8; ++dt) oacc[dt] = (f32x4){0.f, 0.f, 0.f, 0.f};

  const int qg0 = qt * 64 + w * 16 + g * 4;
  const int tmax = qt;

  stage_K(lK, Kp, b, h, 0, w, lane);
  stage_V(lV, Vt, bh, 0, w, lane);

  for (int t = 0; t <= tmax; ++t) {
    asm volatile("s_waitcnt vmcnt(4)" ::: "memory");
    __builtin_amdgcn_s_barrier();
    __builtin_amdgcn_sched_barrier(0);

    f32x4 s[4];
#pragma unroll
    for (int ct = 0; ct < 4; ++ct) s[ct] = (f32x4){0.f, 0.f, 0.f, 0.f};
#pragma unroll
    for (int ct = 0; ct < 4; ++ct)
#pragma unroll
      for (int kc = 0; kc < 4; ++kc) {
        bf16x8 kf = *reinterpret_cast<const bf16x8*>(&lK[kc * 2048 + (ct * 16 + rl) * 32 + gx8]);
        s[ct] = __builtin_amdgcn_mfma_f32_16x16x32_bf16(qf[kc], kf, s[ct], 0, 0, 0);
      }
    asm volatile("s_waitcnt lgkmcnt(0)" ::: "memory");
    __builtin_amdgcn_sched_barrier(0);
    __builtin_amdgcn_s_barrier();

    if (t < tmax) stage_K(lK, Kp, b, h, t + 1, w, lane);

    if (t < tmax) asm volatile("s_waitcnt vmcnt(4)" ::: "memory");
    else          asm volatile("s_waitcnt vmcnt(0)" ::: "memory");
    __builtin_amdgcn_s_barrier();
    __builtin_amdgcn_sched_barrier(0);

    if (t == qt) {
#pragma unroll
      for (int ct = 0; ct < 4; ++ct) {
        int kg = t * 64 + ct * 16 + rl;
#pragma unroll
        for (int j = 0; j < 4; ++j)
          if (kg > qg0 + j) s[ct][j] = -1e30f;
      }
    }
    float mx[4], al[4];
#pragma unroll
    for (int j = 0; j < 4; ++j)
      mx[j] = fmaxf(fmaxf(s[0][j], s[1][j]), fmaxf(s[2][j], s[3][j]));
#pragma unroll
    for (int off = 1; off < 16; off <<= 1)
#pragma unroll
      for (int j = 0; j < 4; ++j) mx[j] = fmaxf(mx[j], __shfl_xor(mx[j], off));
#pragma unroll
    for (int j = 0; j < 4; ++j) {
      float mn = fmaxf(m[j], mx[j]);
      al[j] = __expf(m[j] - mn);
      m[j] = mn;
    }
    float rs[4] = {0.f, 0.f, 0.f, 0.f};
#pragma unroll
    for (int ct = 0; ct < 4; ++ct)
#pragma unroll
      for (int j = 0; j < 4; ++j) {
        float p = __expf(s[ct][j] - m[j]);
        s[ct][j] = p;
        rs[j] += p;
      }
#pragma unroll
    for (int off = 1; off < 16; off <<= 1)
#pragma unroll
      for (int j = 0; j < 4; ++j) rs[j] += __shfl_xor(rs[j], off);
#pragma unroll
    for (int j = 0; j < 4; ++j) l[j] = l[j] * al[j] + rs[j];
#pragma unroll
    for (int dt = 0; dt < 8; ++dt)
#pragma unroll
      for (int j = 0; j < 4; ++j) oacc[dt][j] *= al[j];

#pragma unroll
    for (int ct = 0; ct < 4; ++ct)
#pragma unroll
      for (int j = 0; j < 4; ++j) plds[w][g * 4 + j][ct * 16 + rl] = f2b(s[ct][j]);

    bf16x8 pa[2];
#pragma unroll
    for (int kc2 = 0; kc2 < 2; ++kc2)
      pa[kc2] = *reinterpret_cast<const bf16x8*>(&plds[w][rl][kc2 * 32 + g * 8]);

#pragma unroll
    for (int dt = 0; dt < 8; ++dt)
#pragma unroll
      for (int kc2 = 0; kc2 < 2; ++kc2) {
        bf16x8 vf = *reinterpret_cast<const bf16x8*>(&lV[kc2 * 4096 + (dt * 16 + rl) * 32 + gx8]);
        oacc[dt] = __builtin_amdgcn_mfma_f32_16x16x32_bf16(pa[kc2], vf, oacc[dt], 0, 0, 0);
      }

    asm volatile("s_waitcnt lgkmcnt(0)" ::: "memory");
    __builtin_amdgcn_sched_barrier(0);
    __builtin_amdgcn_s_barrier();

    if (t < tmax) stage_V(lV, Vt, bh, t + 1, w, lane);
  }

  float inv[4];
#pragma unroll
  for (int j = 0; j < 4; ++j) inv[j] = 1.f / l[j];
#pragma unroll
  for (int dt = 0; dt < 8; ++dt)
#pragma unroll
    for (int j = 0; j < 4; ++j)
      O[(qrow + g * 4 + j) * DIM + h * HDIM + dt * 16 + rl] = f2b(oacc[dt][j] * inv[j]);
}

// ---------------- RMSNorm: fp32 in, fp32 weight; out bf16 or fp32 ----------------
__global__ __launch_bounds__(256) void rmsnorm_to_bf16(const float* __restrict__ X, const float* __restrict__ W,
                                                       u16* __restrict__ O) {
  int row = blockIdx.x, tid = threadIdx.x;
  const float* xr = X + (size_t)row * DIM + tid * 8;
  float4 a = *(const float4*)xr;
  float4 bq = *(const float4*)(xr + 4);
  float v[8] = {a.x, a.y, a.z, a.w, bq.x, bq.y, bq.z, bq.w};
  float ss = 0.f;
#pragma unroll
  for (int j = 0; j < 8; ++j) ss += v[j] * v[j];
#pragma unroll
  for (int off = 32; off; off >>= 1) ss += __shfl_xor(ss, off);
  __shared__ float wss[4];
  int wave = tid >> 6, lane = tid & 63;
  if (lane == 0) wss[wave] = ss;
  __syncthreads();
  float r = rsqrtf((wss[0] + wss[1] + wss[2] + wss[3]) * (1.f / DIM) + 1e-6f);
  float4 wa = *(const float4*)(W + tid * 8);
  float4 wb = *(const float4*)(W + tid * 8 + 4);
  float wv[8] = {wa.x, wa.y, wa.z, wa.w, wb.x, wb.y, wb.z, wb.w};
  uint4 ou;
  ou.x = (u32)f2b(v[0] * r * wv[0]) | ((u32)f2b(v[1] * r * wv[1]) << 16);
  ou.y = (u32)f2b(v[2] * r * wv[2]) | ((u32)f2b(v[3] * r * wv[3]) << 16);
  ou.z = (u32)f2b(v[4] * r * wv[4]) | ((u32)f2b(v[5] * r * wv[5]) << 16);
  ou.w = (u32)f2b(v[6] * r * wv[6]) | ((u32)f2b(v[7] * r * wv[7]) << 16);
  *(uint4*)(O + (size_t)row * DIM + tid * 8) = ou;
}

__global__ __launch_bounds__(256) void rmsnorm_to_f32(const float* __restrict__ X, const float* __restrict__ W,
                                                      float* __restrict__ O) {
  int row = blockIdx.x, tid = threadIdx.x;
  const float* xr = X + (size_t)row * DIM + tid * 8;
  float4 a = *(const float4*)xr;
  float4 bq = *(const float4*)(xr + 4);
  float v[8] = {a.x, a.y, a.z, a.w, bq.x, bq.y, bq.z, bq.w};
  float ss = 0.f;
#pragma unroll
  for (int j = 0; j < 8; ++j) ss += v[j] * v[j];
#pragma unroll
  for (int off = 32; off; off >>= 1) ss += __shfl_xor(ss, off);
  __shared__ float wss[4];
  int wave = tid >> 6, lane = tid & 63;
  if (lane == 0) wss[wave] = ss;
  __syncthreads();
  float r = rsqrtf((wss[0] + wss[1] + wss[2] + wss[3]) * (1.f / DIM) + 1e-6f);
  float4 wa = *(const float4*)(W + tid * 8);
  float4 wb = *(const float4*)(W + tid * 8 + 4);
  float wv[8] = {wa.x, wa.y, wa.z, wa.w, wb.x, wb.y, wb.z, wb.w};
  float4 o0 = {v[0] * r * wv[0], v[1] * r * wv[1], v[2] * r * wv[2], v[3] * r * wv[3]};
  float4 o1 = {v[4] * r * wv[4], v[5] * r * wv[5], v[6] * r * wv[6], v[7] * r * wv[7]};
  *(float4*)(O + (size_t)row * DIM + tid * 8) = o0;
  *(float4*)(O + (size_t)row * DIM + tid * 8 + 4) = o1;
}

// ---------------- launch ----------------
// Workspace layout (u16 units), peak 73.4M u16 = 146.8 MB (proven safe):
//   [0,SZ) xb -> later x1f/x2f (fp32 over [0,2SZ)); [SZ,2SZ) q; [2SZ,3SZ) k;
//   [3SZ,4SZ) v; [4SZ,5SZ) vt; [5SZ,6SZ) hb; [6SZ,+23.07M) weights (time-muxed)
extern "C" void kernel_launch(void* const* d_in, const int* in_sizes, int n_in,
                              void* d_out, int out_size, void* d_ws, size_t ws_size,
                              hipStream_t stream) {
  const float* x     = (const float*)d_in[0];
  const float* wq    = (const float*)d_in[1];
  const float* wk    = (const float*)d_in[2];
  const float* wv    = (const float*)d_in[3];
  const float* wo    = (const float*)d_in[4];
  const float* w_mlp = (const float*)d_in[5];
  const float* v_mlp = (const float*)d_in[6];
  const float* w2    = (const float*)d_in[7];
  const float* n1w   = (const float*)d_in[8];
  const float* n2w   = (const float*)d_in[9];
  const float* fcos  = (const float*)d_in[10];
  const float* fsin  = (const float*)d_in[11];

  u16* ws = (u16*)d_ws;
  const size_t SZ = (size_t)ROWS * DIM;
  const size_t DD = (size_t)DIM * DIM;
  const size_t DH = (size_t)DIM * HIDDEN;

  u16* xb  = ws;
  u16* q   = ws + SZ;
  u16* k   = ws + 2 * SZ;
  u16* v   = ws + 3 * SZ;
  u16* vt  = ws + 4 * SZ;
  u16* hb  = ws + 5 * SZ;
  u16* W   = ws + 6 * SZ;
  u16* wqT = W;
  u16* wkT = W + DD;
  u16* wvT = W + 2 * DD;
  u16* woT = W + 3 * DD;
  u16* wmb = W;
  u16* vmb = W + DH;
  u16* w2b = W;
  float* x1f = (float*)ws;
  float* x2f = (float*)ws;
  u16* ba  = ws + 2 * SZ;

  dim3 blk(256);
  dim3 blk8(512);

  // phase 0: input + attn weight conversion (4 transposes fused into one launch)
  cvt_f2b<<<(int)(SZ / 4 / 256), blk, 0, stream>>>(x, xb, (int)SZ);
  cvtT4<<<dim3(DIM / 32, DIM / 32, 4), blk, 0, stream>>>(wq, wk, wv, wo, wqT, wkT, wvT, woT);

  // fused QKV projection + RoPE in epilogue: split store into q,k,v (q,k pre-rotated)
  dim3 gQKV(3 * DIM / 256, ROWS / 128);
  gemm8p<5><<<gQKV, blk8, 0, stream>>>(xb, W, nullptr, q, ROWS, 3 * DIM, DIM, fcos, fsin);

  cvt_f2b<<<(int)(DH / 4 / 256), blk, 0, stream>>>(w_mlp, wmb, (int)DH);

  vtrans<<<dim3(SEQ / 32, HDIM / 32, BATCH * NHEAD), blk, 0, stream>>>(v, vt);

  // flash attention: 1024 blocks, 3/CU; out -> v buffer
  attn_kernel<<<dim3(SEQ / 64, BATCH * NHEAD), blk, 0, stream>>>(q, k, vt, v);

  // o-proj + fp32 residual x -> x1f
  dim3 gP(DIM / 256, ROWS / 128);
  gemm8p<1><<<gP, blk8, 0, stream>>>(v, woT, x, x1f, ROWS, DIM, DIM, nullptr, nullptr);

  cvt_f2b<<<(int)(DH / 4 / 256), blk, 0, stream>>>(v_mlp, vmb, (int)DH);

  rmsnorm_to_bf16<<<ROWS, blk, 0, stream>>>(x1f, n1w, hb);

  // fused MLP up+gate: ba = silu(hb@wmb^T) * (hb@vmb^T)
  dim3 gM(HIDDEN / 256, ROWS / 128);
  gemm_mlp<<<gM, blk8, 0, stream>>>(hb, wmb, vmb, ba, ROWS, HIDDEN, DIM);

  cvt_f2b<<<(int)(DH / 4 / 256), blk, 0, stream>>>(w2, w2b, (int)DH);

  // down-proj + bf16 residual h -> x2f
  gemm8p<3><<<gP, blk8, 0, stream>>>(ba, w2b, hb, x2f, ROWS, DIM, HIDDEN, nullptr, nullptr);
  rmsnorm_to_f32<<<ROWS, blk, 0, stream>>>(x2f, n2w, (float*)d_out);
}

// Round 14
// 770.882 us; speedup vs baseline: 1.0306x; 1.0306x over previous
//
#include <hip/hip_runtime.h>

typedef unsigned short u16;
typedef unsigned int u32;
typedef float f32x4 __attribute__((ext_vector_type(4)));
typedef short bf16x8 __attribute__((ext_vector_type(8)));

#define DIM 2048
#define SEQ 2048
#define NHEAD 16
#define HDIM 128
#define BATCH 2
#define HIDDEN 5632
#define ROWS 4096  // BATCH*SEQ

__device__ __forceinline__ float b2f(u16 h) { return __uint_as_float(((u32)h) << 16); }
__device__ __forceinline__ u16 f2b(float f) {
  u32 u = __float_as_uint(f);
  return (u16)((u + 0x7fffu + ((u >> 16) & 1u)) >> 16);
}

// ---------------- fp32 -> bf16 elementwise ----------------
__global__ __launch_bounds__(256) void cvt_f2b(const float* __restrict__ in, u16* __restrict__ out, int n) {
  int i = (blockIdx.x * 256 + threadIdx.x) * 4;
  if (i < n) {
    float4 v = *(const float4*)(in + i);
    u32 p0 = (u32)f2b(v.x) | ((u32)f2b(v.y) << 16);
    u32 p1 = (u32)f2b(v.z) | ((u32)f2b(v.w) << 16);
    *(uint2*)(out + i) = make_uint2(p0, p1);
  }
}

// ---------------- 4x fused: fp32 [2048,2048] -> bf16 transposed, z picks the weight ----------------
__global__ __launch_bounds__(256) void cvtT4(const float* __restrict__ w0, const float* __restrict__ w1,
                                             const float* __restrict__ w2, const float* __restrict__ w3,
                                             u16* __restrict__ o0, u16* __restrict__ o1,
                                             u16* __restrict__ o2, u16* __restrict__ o3) {
  const float* in = (blockIdx.z == 0) ? w0 : (blockIdx.z == 1) ? w1 : (blockIdx.z == 2) ? w2 : w3;
  u16* out = (blockIdx.z == 0) ? o0 : (blockIdx.z == 1) ? o1 : (blockIdx.z == 2) ? o2 : o3;
  __shared__ float t[32][33];
  int tx = threadIdx.x & 31, ty = threadIdx.x >> 5;
  int r0 = blockIdx.y * 32, c0 = blockIdx.x * 32;
#pragma unroll
  for (int rr = 0; rr < 4; ++rr)
    t[ty + rr * 8][tx] = in[(size_t)(r0 + ty + rr * 8) * DIM + c0 + tx];
  __syncthreads();
#pragma unroll
  for (int rr = 0; rr < 4; ++rr)
    out[(size_t)(c0 + ty + rr * 8) * DIM + r0 + tx] = f2b(t[tx][ty + rr * 8]);
}

// ================= gemm8p v2 (round-8 config): BM=128 x BN=256, BK=64 =================
// EPI: 0 bf16; 1 fp32 C=acc+fp32 R; 2 bf16 C=silu(R)*acc; 3 fp32 C=acc+bf16 R; 4 QKV split
template <int EPI>
__global__ __launch_bounds__(512, 2) void gemm8p(const u16* __restrict__ A, const u16* __restrict__ Bt,
                                                 const void* R_, void* C_, int M, int N, int K) {
  __shared__ u16 LA[2][8192];
  __shared__ u16 LB[2][2][8192];
  const int tid = threadIdx.x;
  const int lane = tid & 63, wid = tid >> 6;
  const int wr = wid >> 2, wc = wid & 3;
  const int rl = lane & 15, g = lane >> 4;
  const int s2 = ((rl >> 3) & 1) << 1;
  const int gx = gridDim.x, gy = gridDim.y;
  const int id = blockIdx.y * gx + blockIdx.x;
  const int cpx = (gx * gy) >> 3;
  const int sw = (id & 7) * cpx + (id >> 3);
  const int m0 = (sw % gy) * 128, n0 = (sw / gy) * 256;
  const int nk = K >> 6;

  const int srow = tid >> 2;
  const int sslot = (tid & 3) ^ (((tid >> 5) & 1) << 1);

  auto SHA = [&](int ks) {
    const u16* gp = A + (size_t)(m0 + srow) * K + ks * 64 + sslot * 8;
#pragma unroll
    for (int kk = 0; kk < 2; ++kk)
      __builtin_amdgcn_global_load_lds(
          (const __attribute__((address_space(1))) void*)(gp + kk * 32),
          (__attribute__((address_space(3))) void*)&LA[ks & 1][kk * 4096 + wid * 512], 16, 0, 0);
  };
  auto SHB = [&](int ks, int hf) {
    const u16* gp = Bt + (size_t)(n0 + hf * 128 + srow) * K + ks * 64 + sslot * 8;
#pragma unroll
    for (int kk = 0; kk < 2; ++kk)
      __builtin_amdgcn_global_load_lds(
          (const __attribute__((address_space(1))) void*)(gp + kk * 32),
          (__attribute__((address_space(3))) void*)&LB[ks & 1][hf][kk * 4096 + wid * 512], 16, 0, 0);
  };

  f32x4 acc[4][4];
#pragma unroll
  for (int a = 0; a < 4; ++a)
#pragma unroll
    for (int b = 0; b < 4; ++b) acc[a][b] = (f32x4){0.f, 0.f, 0.f, 0.f};
  bf16x8 bf[4][2];

#define PH8(kst, q, STAGE, VMN)                                                                 \
  do {                                                                                          \
    const int c_ = (kst) & 1;                                                                   \
    if ((q) == 0) {                                                                             \
      _Pragma("unroll") for (int ni = 0; ni < 4; ++ni)                                          \
          _Pragma("unroll") for (int kk = 0; kk < 2; ++kk)                                      \
              bf[ni][kk] = *(const bf16x8*)&LB[c_][wc >> 1]                                     \
                  [kk * 4096 + ((wc & 1) * 64 + ni * 16 + rl) * 32 + (g ^ s2) * 8];             \
    }                                                                                           \
    bf16x8 af[2];                                                                               \
    _Pragma("unroll") for (int kk = 0; kk < 2; ++kk)                                            \
        af[kk] = *(const bf16x8*)&LA[c_]                                                        \
            [kk * 4096 + (wr * 64 + (q) * 16 + rl) * 32 + (g ^ s2) * 8];                        \
    STAGE;                                                                                      \
    __builtin_amdgcn_s_barrier();                                                               \
    asm volatile("s_waitcnt lgkmcnt(0)" ::: "memory");                                          \
    __builtin_amdgcn_sched_barrier(0);                                                          \
    __builtin_amdgcn_s_setprio(1);                                                              \
    _Pragma("unroll") for (int kk = 0; kk < 2; ++kk)                                            \
        _Pragma("unroll") for (int ni = 0; ni < 4; ++ni)                                        \
            acc[(q)][ni] = __builtin_amdgcn_mfma_f32_16x16x32_bf16(                             \
                af[kk], bf[ni][kk], acc[(q)][ni], 0, 0, 0);                                     \
    __builtin_amdgcn_s_setprio(0);                                                              \
    if ((VMN) == 4) asm volatile("s_waitcnt vmcnt(4)" ::: "memory");                            \
    else if ((VMN) == 6) asm volatile("s_waitcnt vmcnt(6)" ::: "memory");                       \
    else if ((VMN) == 0) asm volatile("s_waitcnt vmcnt(0)" ::: "memory");                       \
    __builtin_amdgcn_s_barrier();                                                               \
  } while (0)

  SHB(0, 0); SHB(0, 1); SHA(0); SHB(1, 0); SHB(1, 1); SHA(1);
  asm volatile("s_waitcnt vmcnt(6)" ::: "memory");
  __builtin_amdgcn_s_barrier();

  const int nk2 = nk >> 1;
  for (int i = 0; i < nk2; ++i) {
    const int k0 = 2 * i, k1 = 2 * i + 1;
    const bool st = (k0 + 2) < nk;
    PH8(k0, 0, , -1);
    PH8(k0, 1, if (st) SHB(k0 + 2, 0), -1);
    PH8(k0, 2, if (st) SHB(k0 + 2, 1), -1);
    PH8(k0, 3, , st ? 4 : 0);
    PH8(k1, 0, if (st) SHA(k0 + 2), -1);
    PH8(k1, 1, if (st) SHB(k0 + 3, 0), -1);
    PH8(k1, 2, if (st) SHB(k0 + 3, 1), -1);
    PH8(k1, 3, if (st) SHA(k0 + 3), st ? 6 : 0);
  }
#undef PH8

#pragma unroll
  for (int mi = 0; mi < 4; ++mi)
#pragma unroll
    for (int ni = 0; ni < 4; ++ni)
#pragma unroll
      for (int j = 0; j < 4; ++j) {
        size_t row = m0 + wr * 64 + mi * 16 + g * 4 + j;
        size_t col = n0 + wc * 64 + ni * 16 + rl;
        size_t idx = row * N + col;
        float v = acc[mi][ni][j];
        if (EPI == 0) {
          ((u16*)C_)[idx] = f2b(v);
        } else if (EPI == 1) {
          ((float*)C_)[idx] = v + ((const float*)R_)[idx];
        } else if (EPI == 2) {
          float av = b2f(((const u16*)R_)[idx]);
          ((u16*)C_)[idx] = f2b(v * av / (1.f + __expf(-av)));
        } else if (EPI == 3) {
          ((float*)C_)[idx] = v + b2f(((const u16*)R_)[idx]);
        } else {  // EPI == 4: QKV split store
          size_t di = (col >> 11) * (size_t)(ROWS * (size_t)DIM) + row * DIM + (col & (DIM - 1));
          ((u16*)C_)[di] = f2b(v);
        }
      }
}

// ================= gemm_mlp: fused MLP up+gate, dual-B, silu(a)*b epilogue =================
__global__ __launch_bounds__(512, 2) void gemm_mlp(const u16* __restrict__ A, const u16* __restrict__ B1t,
                                                   const u16* __restrict__ B2t, u16* __restrict__ C,
                                                   int M, int N, int K) {
  __shared__ u16 lA[2][4096];
  __shared__ u16 lB1[2][8192];
  __shared__ u16 lB2[2][8192];
  const int tid = threadIdx.x;
  const int lane = tid & 63, wid = tid >> 6;
  const int wr = wid >> 2, wc = wid & 3;
  const int rl = lane & 15, g = lane >> 4;
  const int s2 = ((rl >> 3) & 1) << 1;
  const int gx = gridDim.x, gy = gridDim.y;
  const int id = blockIdx.y * gx + blockIdx.x;
  const int cpx = (gx * gy) >> 3;
  const int sw = (id & 7) * cpx + (id >> 3);
  const int m0 = (sw % gy) * 128, n0 = (sw / gy) * 256;
  const int nk = K >> 5;

  const int srow = tid >> 2;
  const int sslot = (tid & 3) ^ (((tid >> 5) & 1) << 1);

  auto SA = [&](int kt, int buf) {
    const u16* gp = A + (size_t)(m0 + srow) * K + kt * 32 + sslot * 8;
    __builtin_amdgcn_global_load_lds((const __attribute__((address_space(1))) void*)gp,
                                     (__attribute__((address_space(3))) void*)&lA[buf][wid * 512],
                                     16, 0, 0);
  };
  auto SB = [&](const u16* __restrict__ Bt, u16* lb, int kt) {
#pragma unroll
    for (int j = 0; j < 2; ++j) {
      const u16* gp = Bt + (size_t)(n0 + j * 128 + srow) * K + kt * 32 + sslot * 8;
      __builtin_amdgcn_global_load_lds((const __attribute__((address_space(1))) void*)gp,
                                       (__attribute__((address_space(3))) void*)(lb + j * 4096 + wid * 512),
                                       16, 0, 0);
    }
  };

  SA(0, 0); SB(B1t, lB1[0], 0); SB(B2t, lB2[0], 0);

  f32x4 ac1[4][4], ac2[4][4];
#pragma unroll
  for (int a = 0; a < 4; ++a)
#pragma unroll
    for (int b = 0; b < 4; ++b) { ac1[a][b] = (f32x4){0.f, 0.f, 0.f, 0.f}; ac2[a][b] = (f32x4){0.f, 0.f, 0.f, 0.f}; }

  __syncthreads();

  for (int kt = 0; kt < nk; ++kt) {
    const int cur = kt & 1;
    if (kt + 1 < nk) { SA(kt + 1, cur ^ 1); SB(B1t, lB1[cur ^ 1], kt + 1); SB(B2t, lB2[cur ^ 1], kt + 1); }
    bf16x8 af[4], b1[4], b2[4];
#pragma unroll
    for (int mi = 0; mi < 4; ++mi)
      af[mi] = *reinterpret_cast<const bf16x8*>(&lA[cur][(wr * 64 + mi * 16 + rl) * 32 + (g ^ s2) * 8]);
#pragma unroll
    for (int ni = 0; ni < 4; ++ni) {
      b1[ni] = *reinterpret_cast<const bf16x8*>(&lB1[cur][(wc * 64 + ni * 16 + rl) * 32 + (g ^ s2) * 8]);
      b2[ni] = *reinterpret_cast<const bf16x8*>(&lB2[cur][(wc * 64 + ni * 16 + rl) * 32 + (g ^ s2) * 8]);
    }
#pragma unroll
    for (int mi = 0; mi < 4; ++mi)
#pragma unroll
      for (int ni = 0; ni < 4; ++ni) {
        ac1[mi][ni] = __builtin_amdgcn_mfma_f32_16x16x32_bf16(af[mi], b1[ni], ac1[mi][ni], 0, 0, 0);
        ac2[mi][ni] = __builtin_amdgcn_mfma_f32_16x16x32_bf16(af[mi], b2[ni], ac2[mi][ni], 0, 0, 0);
      }
    __syncthreads();
  }

#pragma unroll
  for (int mi = 0; mi < 4; ++mi)
#pragma unroll
    for (int ni = 0; ni < 4; ++ni)
#pragma unroll
      for (int j = 0; j < 4; ++j) {
        size_t row = m0 + wr * 64 + mi * 16 + g * 4 + j;
        size_t col = n0 + wc * 64 + ni * 16 + rl;
        float a = ac1[mi][ni][j], b = ac2[mi][ni][j];
        C[row * N + col] = f2b(a / (1.f + __expf(-a)) * b);
      }
}

// ---------------- V [B,S,H,D] bf16 -> Vt [B,H,D,S] bf16 ----------------
__global__ __launch_bounds__(256) void vtrans(const u16* __restrict__ V, u16* __restrict__ Vt) {
  __shared__ u16 t[32][33];
  int tx = threadIdx.x & 31, ty = threadIdx.x >> 5;
  int s0 = blockIdx.x * 32, d0 = blockIdx.y * 32;
  int bh = blockIdx.z, b = bh >> 4, h = bh & 15;
#pragma unroll
  for (int rr = 0; rr < 4; ++rr)
    t[ty + rr * 8][tx] = V[(size_t)(b * SEQ + s0 + ty + rr * 8) * DIM + h * HDIM + d0 + tx];
  __syncthreads();
#pragma unroll
  for (int rr = 0; rr < 4; ++rr)
    Vt[(size_t)(bh * HDIM + d0 + ty + rr * 8) * SEQ + s0 + tx] = t[tx][ty + rr * 8];
}

// ---------------- RoPE in-place on bf16 q,k; fp32 cos/sin; q scaled 1/sqrt(HDIM) ----------------
__global__ __launch_bounds__(256) void rope_kernel(u16* __restrict__ Q, u16* __restrict__ Kv,
                                                   const float* __restrict__ Cz, const float* __restrict__ Sz) {
  int t = blockIdx.x * 256 + threadIdx.x;
  int i = t & 63;
  int hh = (t >> 6) & 15;
  int row = t >> 10;
  int s = row & (SEQ - 1);
  float c = Cz[s * 64 + i], sn = Sz[s * 64 + i];
  size_t off = (size_t)row * DIM + hh * HDIM + 2 * i;
  const float sc = 0.08838834764831843f;

  u32 qp = *(const u32*)(Q + off);
  float q0 = b2f((u16)qp), q1 = b2f((u16)(qp >> 16));
  float o0 = (q0 * c - q1 * sn) * sc, o1 = (q0 * sn + q1 * c) * sc;
  *(u32*)(Q + off) = (u32)f2b(o0) | ((u32)f2b(o1) << 16);

  u32 kp = *(const u32*)(Kv + off);
  float k0 = b2f((u16)kp), k1 = b2f((u16)(kp >> 16));
  o0 = k0 * c - k1 * sn; o1 = k0 * sn + k1 * c;
  *(u32*)(Kv + off) = (u32)f2b(o0) | ((u32)f2b(o1) << 16);
}

// ---------------- flash attention (causal), r7/r11 structure ----------------
__device__ __forceinline__ void stage_K(u16* lk, const u16* __restrict__ Kg,
                                        int b, int h, int t, int w, int lane) {
  const int r4 = lane >> 2;
  const int gsw = (lane & 3) ^ (r4 & 3);
#pragma unroll
  for (int j = 0; j < 4; ++j) {
    const u16* gp = Kg + (size_t)(b * SEQ + t * 64 + j * 16 + r4) * DIM +
                    h * HDIM + w * 32 + gsw * 8;
    __builtin_amdgcn_global_load_lds((const __attribute__((address_space(1))) void*)gp,
                                     (__attribute__((address_space(3))) void*)(lk + w * 2048 + j * 512),
                                     16, 0, 0);
  }
}

__device__ __forceinline__ void stage_V(u16* lv, const u16* __restrict__ Vg,
                                        int bh, int t, int w, int lane) {
  const int r4 = lane >> 2;
  const int gsw = (lane & 3) ^ (r4 & 3);
#pragma unroll
  for (int j = 0; j < 4; ++j) {
    int id = w * 4 + j, kc2 = id >> 3, rg = id & 7;
    const u16* gp = Vg + (size_t)(bh * HDIM + rg * 16 + r4) * SEQ +
                    t * 64 + kc2 * 32 + gsw * 8;
    __builtin_amdgcn_global_load_lds((const __attribute__((address_space(1))) void*)gp,
                                     (__attribute__((address_space(3))) void*)(lv + kc2 * 4096 + rg * 512),
                                     16, 0, 0);
  }
}

__global__ __launch_bounds__(256, 3) void attn_kernel(const u16* __restrict__ Q, const u16* __restrict__ Kp,
                                                      const u16* __restrict__ Vt, u16* __restrict__ O) {
  const int lane = threadIdx.x & 63;
  const int w = threadIdx.x >> 6;
  const int id = blockIdx.y * 32 + blockIdx.x;
  const int sw = (id & 7) * 128 + (id >> 3);
  const int qt = sw & 31;
  const int bh = sw >> 5;
  const int b = bh >> 4, h = bh & 15;
  const int rl = lane & 15, g = lane >> 4;
  const int gx8 = (g ^ (rl & 3)) * 8;

  __shared__ u16 lK[8192];
  __shared__ u16 lV[8192];
  __shared__ u16 plds[4][16][72];

  const size_t qrow = (size_t)b * SEQ + qt * 64 + w * 16;
  bf16x8 qf[4];
#pragma unroll
  for (int kc = 0; kc < 4; ++kc)
    qf[kc] = *reinterpret_cast<const bf16x8*>(Q + (qrow + rl) * DIM + h * HDIM + kc * 32 + g * 8);

  float m[4], l[4];
  f32x4 oacc[8];
#pragma unroll
  for (int j = 0; j < 4; ++j) { m[j] = -1e30f; l[j] = 0.f; }
#pragma unroll
  for (int dt = 0; dt < 8; ++dt) oacc[dt] = (f32x4){0.f, 0.f, 0.f, 0.f};

  const int qg0 = qt * 64 + w * 16 + g * 4;
  const int tmax = qt;

  stage_K(lK, Kp, b, h, 0, w, lane);
  stage_V(lV, Vt, bh, 0, w, lane);

  for (int t = 0; t <= tmax; ++t) {
    asm volatile("s_waitcnt vmcnt(4)" ::: "memory");
    __builtin_amdgcn_s_barrier();
    __builtin_amdgcn_sched_barrier(0);

    f32x4 s[4];
#pragma unroll
    for (int ct = 0; ct < 4; ++ct) s[ct] = (f32x4){0.f, 0.f, 0.f, 0.f};
#pragma unroll
    for (int ct = 0; ct < 4; ++ct)
#pragma unroll
      for (int kc = 0; kc < 4; ++kc) {
        bf16x8 kf = *reinterpret_cast<const bf16x8*>(&lK[kc * 2048 + (ct * 16 + rl) * 32 + gx8]);
        s[ct] = __builtin_amdgcn_mfma_f32_16x16x32_bf16(qf[kc], kf, s[ct], 0, 0, 0);
      }
    asm volatile("s_waitcnt lgkmcnt(0)" ::: "memory");
    __builtin_amdgcn_sched_barrier(0);
    __builtin_amdgcn_s_barrier();

    if (t < tmax) stage_K(lK, Kp, b, h, t + 1, w, lane);

    if (t < tmax) asm volatile("s_waitcnt vmcnt(4)" ::: "memory");
    else          asm volatile("s_waitcnt vmcnt(0)" ::: "memory");
    __builtin_amdgcn_s_barrier();
    __builtin_amdgcn_sched_barrier(0);

    if (t == qt) {
#pragma unroll
      for (int ct = 0; ct < 4; ++ct) {
        int kg = t * 64 + ct * 16 + rl;
#pragma unroll
        for (int j = 0; j < 4; ++j)
          if (kg > qg0 + j) s[ct][j] = -1e30f;
      }
    }
    float mx[4], al[4];
#pragma unroll
    for (int j = 0; j < 4; ++j)
      mx[j] = fmaxf(fmaxf(s[0][j], s[1][j]), fmaxf(s[2][j], s[3][j]));
#pragma unroll
    for (int off = 1; off < 16; off <<= 1)
#pragma unroll
      for (int j = 0; j < 4; ++j) mx[j] = fmaxf(mx[j], __shfl_xor(mx[j], off));
#pragma unroll
    for (int j = 0; j < 4; ++j) {
      float mn = fmaxf(m[j], mx[j]);
      al[j] = __expf(m[j] - mn);
      m[j] = mn;
    }
    float rs[4] = {0.f, 0.f, 0.f, 0.f};
#pragma unroll
    for (int ct = 0; ct < 4; ++ct)
#pragma unroll
      for (int j = 0; j < 4; ++j) {
        float p = __expf(s[ct][j] - m[j]);
        s[ct][j] = p;
        rs[j] += p;
      }
#pragma unroll
    for (int off = 1; off < 16; off <<= 1)
#pragma unroll
      for (int j = 0; j < 4; ++j) rs[j] += __shfl_xor(rs[j], off);
#pragma unroll
    for (int j = 0; j < 4; ++j) l[j] = l[j] * al[j] + rs[j];
#pragma unroll
    for (int dt = 0; dt < 8; ++dt)
#pragma unroll
      for (int j = 0; j < 4; ++j) oacc[dt][j] *= al[j];

#pragma unroll
    for (int ct = 0; ct < 4; ++ct)
#pragma unroll
      for (int j = 0; j < 4; ++j) plds[w][g * 4 + j][ct * 16 + rl] = f2b(s[ct][j]);

    bf16x8 pa[2];
#pragma unroll
    for (int kc2 = 0; kc2 < 2; ++kc2)
      pa[kc2] = *reinterpret_cast<const bf16x8*>(&plds[w][rl][kc2 * 32 + g * 8]);

#pragma unroll
    for (int dt = 0; dt < 8; ++dt)
#pragma unroll
      for (int kc2 = 0; kc2 < 2; ++kc2) {
        bf16x8 vf = *reinterpret_cast<const bf16x8*>(&lV[kc2 * 4096 + (dt * 16 + rl) * 32 + gx8]);
        oacc[dt] = __builtin_amdgcn_mfma_f32_16x16x32_bf16(pa[kc2], vf, oacc[dt], 0, 0, 0);
      }

    asm volatile("s_waitcnt lgkmcnt(0)" ::: "memory");
    __builtin_amdgcn_sched_barrier(0);
    __builtin_amdgcn_s_barrier();

    if (t < tmax) stage_V(lV, Vt, bh, t + 1, w, lane);
  }

  float inv[4];
#pragma unroll
  for (int j = 0; j < 4; ++j) inv[j] = 1.f / l[j];
#pragma unroll
  for (int dt = 0; dt < 8; ++dt)
#pragma unroll
    for (int j = 0; j < 4; ++j)
      O[(qrow + g * 4 + j) * DIM + h * HDIM + dt * 16 + rl] = f2b(oacc[dt][j] * inv[j]);
}

// ---------------- RMSNorm: fp32 in, fp32 weight; out bf16 or fp32 ----------------
__global__ __launch_bounds__(256) void rmsnorm_to_bf16(const float* __restrict__ X, const float* __restrict__ W,
                                                       u16* __restrict__ O) {
  int row = blockIdx.x, tid = threadIdx.x;
  const float* xr = X + (size_t)row * DIM + tid * 8;
  float4 a = *(const float4*)xr;
  float4 bq = *(const float4*)(xr + 4);
  float v[8] = {a.x, a.y, a.z, a.w, bq.x, bq.y, bq.z, bq.w};
  float ss = 0.f;
#pragma unroll
  for (int j = 0; j < 8; ++j) ss += v[j] * v[j];
#pragma unroll
  for (int off = 32; off; off >>= 1) ss += __shfl_xor(ss, off);
  __shared__ float wss[4];
  int wave = tid >> 6, lane = tid & 63;
  if (lane == 0) wss[wave] = ss;
  __syncthreads();
  float r = rsqrtf((wss[0] + wss[1] + wss[2] + wss[3]) * (1.f / DIM) + 1e-6f);
  float4 wa = *(const float4*)(W + tid * 8);
  float4 wb = *(const float4*)(W + tid * 8 + 4);
  float wv[8] = {wa.x, wa.y, wa.z, wa.w, wb.x, wb.y, wb.z, wb.w};
  uint4 ou;
  ou.x = (u32)f2b(v[0] * r * wv[0]) | ((u32)f2b(v[1] * r * wv[1]) << 16);
  ou.y = (u32)f2b(v[2] * r * wv[2]) | ((u32)f2b(v[3] * r * wv[3]) << 16);
  ou.z = (u32)f2b(v[4] * r * wv[4]) | ((u32)f2b(v[5] * r * wv[5]) << 16);
  ou.w = (u32)f2b(v[6] * r * wv[6]) | ((u32)f2b(v[7] * r * wv[7]) << 16);
  *(uint4*)(O + (size_t)row * DIM + tid * 8) = ou;
}

__global__ __launch_bounds__(256) void rmsnorm_to_f32(const float* __restrict__ X, const float* __restrict__ W,
                                                      float* __restrict__ O) {
  int row = blockIdx.x, tid = threadIdx.x;
  const float* xr = X + (size_t)row * DIM + tid * 8;
  float4 a = *(const float4*)xr;
  float4 bq = *(const float4*)(xr + 4);
  float v[8] = {a.x, a.y, a.z, a.w, bq.x, bq.y, bq.z, bq.w};
  float ss = 0.f;
#pragma unroll
  for (int j = 0; j < 8; ++j) ss += v[j] * v[j];
#pragma unroll
  for (int off = 32; off; off >>= 1) ss += __shfl_xor(ss, off);
  __shared__ float wss[4];
  int wave = tid >> 6, lane = tid & 63;
  if (lane == 0) wss[wave] = ss;
  __syncthreads();
  float r = rsqrtf((wss[0] + wss[1] + wss[2] + wss[3]) * (1.f / DIM) + 1e-6f);
  float4 wa = *(const float4*)(W + tid * 8);
  float4 wb = *(const float4*)(W + tid * 8 + 4);
  float wv[8] = {wa.x, wa.y, wa.z, wa.w, wb.x, wb.y, wb.z, wb.w};
  float4 o0 = {v[0] * r * wv[0], v[1] * r * wv[1], v[2] * r * wv[2], v[3] * r * wv[3]};
  float4 o1 = {v[4] * r * wv[4], v[5] * r * wv[5], v[6] * r * wv[6], v[7] * r * wv[7]};
  *(float4*)(O + (size_t)row * DIM + tid * 8) = o0;
  *(float4*)(O + (size_t)row * DIM + tid * 8 + 4) = o1;
}

// ---------------- launch ----------------
// Workspace layout (u16 units), peak 73.4M u16 = 146.8 MB (proven safe):
//   [0,SZ) xb -> later x1f/x2f (fp32 over [0,2SZ)); [SZ,2SZ) q; [2SZ,3SZ) k;
//   [3SZ,4SZ) v; [4SZ,5SZ) vt; [5SZ,6SZ) hb; [6SZ,+23.07M) weights (time-muxed)
extern "C" void kernel_launch(void* const* d_in, const int* in_sizes, int n_in,
                              void* d_out, int out_size, void* d_ws, size_t ws_size,
                              hipStream_t stream) {
  const float* x     = (const float*)d_in[0];
  const float* wq    = (const float*)d_in[1];
  const float* wk    = (const float*)d_in[2];
  const float* wv    = (const float*)d_in[3];
  const float* wo    = (const float*)d_in[4];
  const float* w_mlp = (const float*)d_in[5];
  const float* v_mlp = (const float*)d_in[6];
  const float* w2    = (const float*)d_in[7];
  const float* n1w   = (const float*)d_in[8];
  const float* n2w   = (const float*)d_in[9];
  const float* fcos  = (const float*)d_in[10];
  const float* fsin  = (const float*)d_in[11];

  u16* ws = (u16*)d_ws;
  const size_t SZ = (size_t)ROWS * DIM;
  const size_t DD = (size_t)DIM * DIM;
  const size_t DH = (size_t)DIM * HIDDEN;

  u16* xb  = ws;
  u16* q   = ws + SZ;
  u16* k   = ws + 2 * SZ;
  u16* v   = ws + 3 * SZ;
  u16* vt  = ws + 4 * SZ;
  u16* hb  = ws + 5 * SZ;
  u16* W   = ws + 6 * SZ;
  u16* wqT = W;
  u16* wkT = W + DD;
  u16* wvT = W + 2 * DD;
  u16* woT = W + 3 * DD;
  u16* wmb = W;
  u16* vmb = W + DH;
  u16* w2b = W;
  float* x1f = (float*)ws;
  float* x2f = (float*)ws;
  u16* ba  = ws + 2 * SZ;

  dim3 blk(256);
  dim3 blk8(512);

  // phase 0: input + attn weight conversion (4 transposes in one launch)
  cvt_f2b<<<(int)(SZ / 4 / 256), blk, 0, stream>>>(x, xb, (int)SZ);
  cvtT4<<<dim3(DIM / 32, DIM / 32, 4), blk, 0, stream>>>(wq, wk, wv, wo, wqT, wkT, wvT, woT);

  // fused QKV projection (r11 config): split store into q,k,v
  dim3 gQKV(3 * DIM / 256, ROWS / 128);
  gemm8p<4><<<gQKV, blk8, 0, stream>>>(xb, W, nullptr, q, ROWS, 3 * DIM, DIM);

  cvt_f2b<<<(int)(DH / 4 / 256), blk, 0, stream>>>(w_mlp, wmb, (int)DH);

  rope_kernel<<<(ROWS * NHEAD * 64) / 256, blk, 0, stream>>>(q, k, fcos, fsin);
  vtrans<<<dim3(SEQ / 32, HDIM / 32, BATCH * NHEAD), blk, 0, stream>>>(v, vt);

  // flash attention: 1024 blocks, 3/CU; out -> v buffer
  attn_kernel<<<dim3(SEQ / 64, BATCH * NHEAD), blk, 0, stream>>>(q, k, vt, v);

  // o-proj + fp32 residual x -> x1f
  dim3 gP(DIM / 256, ROWS / 128);
  gemm8p<1><<<gP, blk8, 0, stream>>>(v, woT, x, x1f, ROWS, DIM, DIM);

  cvt_f2b<<<(int)(DH / 4 / 256), blk, 0, stream>>>(v_mlp, vmb, (int)DH);

  rmsnorm_to_bf16<<<ROWS, blk, 0, stream>>>(x1f, n1w, hb);

  // fused MLP up+gate: ba = silu(hb@wmb^T) * (hb@vmb^T)
  dim3 gM(HIDDEN / 256, ROWS / 128);
  gemm_mlp<<<gM, blk8, 0, stream>>>(hb, wmb, vmb, ba, ROWS, HIDDEN, DIM);

  cvt_f2b<<<(int)(DH / 4 / 256), blk, 0, stream>>>(w2, w2b, (int)DH);

  // down-proj + bf16 residual h -> x2f
  gemm8p<3><<<gP, blk8, 0, stream>>>(ba, w2b, hb, x2f, ROWS, DIM, HIDDEN);
  rmsnorm_to_f32<<<ROWS, blk, 0, stream>>>(x2f, n2w, (float*)d_out);
}